// Round 1
// baseline (121.281 us; speedup 1.0000x reference)
//
#include <hip/hip_runtime.h>
#include <math.h>

// Problem constants: B=2, L=256, D=256, H=4, DH=64.
// Output tuple: out (B,L,D)=131072 floats, then attn (B,H,L,L)=524288 floats.
//
// Key algebraic simplifications (see theory):
//  - logits bias term  qh . (pitch_rel @ pr_w^T)  ==  pitch_rel . (qh @ pr_w_headslice)
//    -> precompute qpr[b,h,i,e] (2048x256), stream pitch_rel once.
//  - pr_b / dr_b contribute a j-constant to logits -> cancels in softmax -> dropped.
//  - 1/sqrt(DH) folded into qh (all logit terms are linear in qh).

// ---------------------------------------------------------------- A0: transpose fc_w
__global__ __launch_bounds__(256) void k_transpose(const float* __restrict__ in,
                                                   float* __restrict__ out) {
  __shared__ float t[32][33];
  int bx = blockIdx.x & 7, by = blockIdx.x >> 3;
  int x = threadIdx.x & 31, y0 = threadIdx.x >> 5;
#pragma unroll
  for (int yy = 0; yy < 32; yy += 8)
    t[yy + y0][x] = in[(size_t)(by * 32 + yy + y0) * 256 + bx * 32 + x];
  __syncthreads();
#pragma unroll
  for (int yy = 0; yy < 32; yy += 8)
    out[(size_t)(bx * 32 + yy + y0) * 256 + by * 32 + x] = t[x][yy + y0];
}

// ---------------------------------------------------------------- A1: q/k/v projections
// y[b,i,o] = sum_e X[b,i,e] * W[o,e] + B[o];  qh scaled by 1/8; stored [b][h][i][d].
__global__ __launch_bounds__(256) void k_proj(
    const float* __restrict__ q, const float* __restrict__ k_, const float* __restrict__ v,
    const float* __restrict__ Wq, const float* __restrict__ Bq,
    const float* __restrict__ Wk, const float* __restrict__ Bk,
    const float* __restrict__ Wv, const float* __restrict__ Bv,
    float* __restrict__ qh, float* __restrict__ kh, float* __restrict__ vh) {
  int blk = blockIdx.x;
  int m = blk >> 5;
  int r = blk & 31;
  int b = r >> 4, it = (r >> 2) & 3, ot = r & 3;
  const float* X = (m == 0) ? q : (m == 1) ? k_ : v;
  const float* W = (m == 0) ? Wq : (m == 1) ? Wk : Wv;
  const float* Bs = (m == 0) ? Bq : (m == 1) ? Bk : Bv;
  float* OUT = (m == 0) ? qh : (m == 1) ? kh : vh;
  const float scale = (m == 0) ? 0.125f : 1.0f;

  __shared__ float xs[64][33];
  __shared__ float ws[64][33];
  int tid = threadIdx.x;
  int ti = tid >> 4, to = tid & 15;
  int lr = tid >> 2, lc = (tid & 3) * 8;
  float acc[4][4] = {};

  for (int k0 = 0; k0 < 256; k0 += 32) {
    float4 a0 = *(const float4*)(X + (size_t)(b * 256 + it * 64 + lr) * 256 + k0 + lc);
    float4 a1 = *(const float4*)(X + (size_t)(b * 256 + it * 64 + lr) * 256 + k0 + lc + 4);
    xs[lr][lc + 0] = a0.x; xs[lr][lc + 1] = a0.y; xs[lr][lc + 2] = a0.z; xs[lr][lc + 3] = a0.w;
    xs[lr][lc + 4] = a1.x; xs[lr][lc + 5] = a1.y; xs[lr][lc + 6] = a1.z; xs[lr][lc + 7] = a1.w;
    float4 w0 = *(const float4*)(W + (size_t)(ot * 64 + lr) * 256 + k0 + lc);
    float4 w1 = *(const float4*)(W + (size_t)(ot * 64 + lr) * 256 + k0 + lc + 4);
    ws[lr][lc + 0] = w0.x; ws[lr][lc + 1] = w0.y; ws[lr][lc + 2] = w0.z; ws[lr][lc + 3] = w0.w;
    ws[lr][lc + 4] = w1.x; ws[lr][lc + 5] = w1.y; ws[lr][lc + 6] = w1.z; ws[lr][lc + 7] = w1.w;
    __syncthreads();
#pragma unroll
    for (int kk = 0; kk < 32; ++kk) {
      float xv0 = xs[ti * 4 + 0][kk], xv1 = xs[ti * 4 + 1][kk];
      float xv2 = xs[ti * 4 + 2][kk], xv3 = xs[ti * 4 + 3][kk];
      float wv0 = ws[0 * 16 + to][kk], wv1 = ws[1 * 16 + to][kk];
      float wv2 = ws[2 * 16 + to][kk], wv3 = ws[3 * 16 + to][kk];
      acc[0][0] += xv0 * wv0; acc[0][1] += xv0 * wv1; acc[0][2] += xv0 * wv2; acc[0][3] += xv0 * wv3;
      acc[1][0] += xv1 * wv0; acc[1][1] += xv1 * wv1; acc[1][2] += xv1 * wv2; acc[1][3] += xv1 * wv3;
      acc[2][0] += xv2 * wv0; acc[2][1] += xv2 * wv1; acc[2][2] += xv2 * wv2; acc[2][3] += xv2 * wv3;
      acc[3][0] += xv3 * wv0; acc[3][1] += xv3 * wv1; acc[3][2] += xv3 * wv2; acc[3][3] += xv3 * wv3;
    }
    __syncthreads();
  }
#pragma unroll
  for (int ii = 0; ii < 4; ++ii)
#pragma unroll
    for (int oo = 0; oo < 4; ++oo) {
      int i = it * 64 + ti * 4 + ii;
      int dd = oo * 16 + to;
      OUT[(size_t)((b * 4 + ot) * 256 + i) * 64 + dd] = (acc[ii][oo] + Bs[ot * 64 + dd]) * scale;
    }
}

// ---------------------------------------------------------------- A2: qpr / qdr
// qpr[r,e] = sum_d qh[r,d] * W[(h*64+d), e], r = (b*4+h)*256 + i, K=64.
__global__ __launch_bounds__(256) void k_qprdr(
    const float* __restrict__ qh, const float* __restrict__ prw,
    const float* __restrict__ drw, float* __restrict__ qpr, float* __restrict__ qdr) {
  int blk = blockIdx.x;  // t*128 + rt*4 + et
  int t = blk >> 7;
  int r2 = blk & 127;
  int rt = r2 >> 2, et = r2 & 3;
  const float* W = t ? drw : prw;
  float* OUT = t ? qdr : qpr;
  int h = (rt >> 2) & 3;

  __shared__ float xs[64][33];
  __shared__ float ws2[32][64];
  int tid = threadIdx.x;
  int ti = tid >> 4, to = tid & 15;
  float acc[4][4] = {};

  for (int k0 = 0; k0 < 64; k0 += 32) {
    int lr = tid >> 2, lc = (tid & 3) * 8;
    float4 a0 = *(const float4*)(qh + (size_t)(rt * 64 + lr) * 64 + k0 + lc);
    float4 a1 = *(const float4*)(qh + (size_t)(rt * 64 + lr) * 64 + k0 + lc + 4);
    xs[lr][lc + 0] = a0.x; xs[lr][lc + 1] = a0.y; xs[lr][lc + 2] = a0.z; xs[lr][lc + 3] = a0.w;
    xs[lr][lc + 4] = a1.x; xs[lr][lc + 5] = a1.y; xs[lr][lc + 6] = a1.z; xs[lr][lc + 7] = a1.w;
    int wr = tid >> 3, wc = (tid & 7) * 8;
    float4 w0 = *(const float4*)(W + (size_t)(h * 64 + k0 + wr) * 256 + et * 64 + wc);
    float4 w1 = *(const float4*)(W + (size_t)(h * 64 + k0 + wr) * 256 + et * 64 + wc + 4);
    ws2[wr][wc + 0] = w0.x; ws2[wr][wc + 1] = w0.y; ws2[wr][wc + 2] = w0.z; ws2[wr][wc + 3] = w0.w;
    ws2[wr][wc + 4] = w1.x; ws2[wr][wc + 5] = w1.y; ws2[wr][wc + 6] = w1.z; ws2[wr][wc + 7] = w1.w;
    __syncthreads();
#pragma unroll
    for (int kk = 0; kk < 32; ++kk) {
      float xv0 = xs[ti * 4 + 0][kk], xv1 = xs[ti * 4 + 1][kk];
      float xv2 = xs[ti * 4 + 2][kk], xv3 = xs[ti * 4 + 3][kk];
      float wv0 = ws2[kk][0 * 16 + to], wv1 = ws2[kk][1 * 16 + to];
      float wv2 = ws2[kk][2 * 16 + to], wv3 = ws2[kk][3 * 16 + to];
      acc[0][0] += xv0 * wv0; acc[0][1] += xv0 * wv1; acc[0][2] += xv0 * wv2; acc[0][3] += xv0 * wv3;
      acc[1][0] += xv1 * wv0; acc[1][1] += xv1 * wv1; acc[1][2] += xv1 * wv2; acc[1][3] += xv1 * wv3;
      acc[2][0] += xv2 * wv0; acc[2][1] += xv2 * wv1; acc[2][2] += xv2 * wv2; acc[2][3] += xv2 * wv3;
      acc[3][0] += xv3 * wv0; acc[3][1] += xv3 * wv1; acc[3][2] += xv3 * wv2; acc[3][3] += xv3 * wv3;
    }
    __syncthreads();
  }
#pragma unroll
  for (int ii = 0; ii < 4; ++ii)
#pragma unroll
    for (int oo = 0; oo < 4; ++oo)
      OUT[(size_t)(rt * 64 + ti * 4 + ii) * 256 + et * 64 + oo * 16 + to] = acc[ii][oo];
}

// ---------------------------------------------------------------- A3: content logits qk
// qk[bh, i, j] = sum_d qh[bh,i,d]*kh[bh,j,d]  (qh already scaled by 1/8); written into attn buf.
__global__ __launch_bounds__(256) void k_qk(const float* __restrict__ qh,
                                            const float* __restrict__ kh,
                                            float* __restrict__ qk) {
  int blk = blockIdx.x;  // bh*16 + it*4 + jt
  int bh = blk >> 4, it = (blk >> 2) & 3, jt = blk & 3;
  __shared__ float xs[64][33];
  __shared__ float ys[64][33];
  int tid = threadIdx.x;
  int ti = tid >> 4, to = tid & 15;
  float acc[4][4] = {};

  for (int k0 = 0; k0 < 64; k0 += 32) {
    int lr = tid >> 2, lc = (tid & 3) * 8;
    float4 a0 = *(const float4*)(qh + (size_t)(bh * 256 + it * 64 + lr) * 64 + k0 + lc);
    float4 a1 = *(const float4*)(qh + (size_t)(bh * 256 + it * 64 + lr) * 64 + k0 + lc + 4);
    xs[lr][lc + 0] = a0.x; xs[lr][lc + 1] = a0.y; xs[lr][lc + 2] = a0.z; xs[lr][lc + 3] = a0.w;
    xs[lr][lc + 4] = a1.x; xs[lr][lc + 5] = a1.y; xs[lr][lc + 6] = a1.z; xs[lr][lc + 7] = a1.w;
    float4 b0 = *(const float4*)(kh + (size_t)(bh * 256 + jt * 64 + lr) * 64 + k0 + lc);
    float4 b1 = *(const float4*)(kh + (size_t)(bh * 256 + jt * 64 + lr) * 64 + k0 + lc + 4);
    ys[lr][lc + 0] = b0.x; ys[lr][lc + 1] = b0.y; ys[lr][lc + 2] = b0.z; ys[lr][lc + 3] = b0.w;
    ys[lr][lc + 4] = b1.x; ys[lr][lc + 5] = b1.y; ys[lr][lc + 6] = b1.z; ys[lr][lc + 7] = b1.w;
    __syncthreads();
#pragma unroll
    for (int kk = 0; kk < 32; ++kk) {
      float xv0 = xs[ti * 4 + 0][kk], xv1 = xs[ti * 4 + 1][kk];
      float xv2 = xs[ti * 4 + 2][kk], xv3 = xs[ti * 4 + 3][kk];
      float wv0 = ys[0 * 16 + to][kk], wv1 = ys[1 * 16 + to][kk];
      float wv2 = ys[2 * 16 + to][kk], wv3 = ys[3 * 16 + to][kk];
      acc[0][0] += xv0 * wv0; acc[0][1] += xv0 * wv1; acc[0][2] += xv0 * wv2; acc[0][3] += xv0 * wv3;
      acc[1][0] += xv1 * wv0; acc[1][1] += xv1 * wv1; acc[1][2] += xv1 * wv2; acc[1][3] += xv1 * wv3;
      acc[2][0] += xv2 * wv0; acc[2][1] += xv2 * wv1; acc[2][2] += xv2 * wv2; acc[2][3] += xv2 * wv3;
      acc[3][0] += xv3 * wv0; acc[3][1] += xv3 * wv1; acc[3][2] += xv3 * wv2; acc[3][3] += xv3 * wv3;
    }
    __syncthreads();
  }
#pragma unroll
  for (int ii = 0; ii < 4; ++ii)
#pragma unroll
    for (int jj = 0; jj < 4; ++jj)
      qk[(size_t)(bh * 256 + it * 64 + ti * 4 + ii) * 256 + jt * 64 + jj * 16 + to] = acc[ii][jj];
}

// ---------------------------------------------------------------- B1: bias stream + softmax (HOT)
// Per block (b,i): stream pitch_rel/dur_rel rows, dot against register-held qpr/qdr,
// add to preloaded qk logits, mask, softmax, write attn.
__global__ __launch_bounds__(256) void k_bias_softmax(
    const float* __restrict__ pitch, const float* __restrict__ dur,
    const float* __restrict__ qpr, const float* __restrict__ qdr,
    const float* __restrict__ amask, const unsigned char* __restrict__ kpm,
    float* __restrict__ attn) {
  int blk = blockIdx.x;
  int b = blk >> 8, i = blk & 255;
  int tid = threadIdx.x, w = tid >> 6, l = tid & 63;

  __shared__ float logits[4][256];
  __shared__ float mflag[256];

  // preload qk row into logits, mask flags, qpr/qdr register fragments
  {
    int hh = tid >> 6, ll = tid & 63;
    float4 qkv = *(const float4*)(attn + (size_t)((b * 4 + hh) * 256 + i) * 256 + 4 * ll);
    *(float4*)&logits[hh][4 * ll] = qkv;
  }
  bool rowmask = kpm[b * 256 + i] != 0;
  mflag[tid] = (rowmask || amask[(size_t)i * 256 + tid] != 0.f) ? 1.f : 0.f;

  float4 qp[4], qd[4];
#pragma unroll
  for (int h = 0; h < 4; ++h) {
    qp[h] = *(const float4*)(qpr + (size_t)((b * 4 + h) * 256 + i) * 256 + 4 * l);
    qd[h] = *(const float4*)(qdr + (size_t)((b * 4 + h) * 256 + i) * 256 + 4 * l);
  }
  __syncthreads();

  const float4* pbase = (const float4*)(pitch + (size_t)(b * 256 + i) * 65536);
  const float4* dbase = (const float4*)(dur + (size_t)(b * 256 + i) * 65536);

  int j = w;
  float4 p = pbase[(size_t)j * 64 + l];
  float4 d4 = dbase[(size_t)j * 64 + l];
  for (int t = 0; t < 64; ++t) {
    float4 pn = make_float4(0.f, 0.f, 0.f, 0.f);
    float4 dn = make_float4(0.f, 0.f, 0.f, 0.f);
    int jn = j + 4;
    if (t < 63) {  // one-ahead prefetch
      pn = pbase[(size_t)jn * 64 + l];
      dn = dbase[(size_t)jn * 64 + l];
    }
    float s[8];
    s[0] = p.x * qp[0].x + p.y * qp[0].y + p.z * qp[0].z + p.w * qp[0].w;
    s[1] = p.x * qp[1].x + p.y * qp[1].y + p.z * qp[1].z + p.w * qp[1].w;
    s[2] = p.x * qp[2].x + p.y * qp[2].y + p.z * qp[2].z + p.w * qp[2].w;
    s[3] = p.x * qp[3].x + p.y * qp[3].y + p.z * qp[3].z + p.w * qp[3].w;
    s[4] = d4.x * qd[0].x + d4.y * qd[0].y + d4.z * qd[0].z + d4.w * qd[0].w;
    s[5] = d4.x * qd[1].x + d4.y * qd[1].y + d4.z * qd[1].z + d4.w * qd[1].w;
    s[6] = d4.x * qd[2].x + d4.y * qd[2].y + d4.z * qd[2].z + d4.w * qd[2].w;
    s[7] = d4.x * qd[3].x + d4.y * qd[3].y + d4.z * qd[3].z + d4.w * qd[3].w;
    // phase 1: reduce all 8 partials within 8-lane groups
#pragma unroll
    for (int m = 1; m <= 4; m <<= 1) {
#pragma unroll
      for (int vv = 0; vv < 8; ++vv) s[vv] += __shfl_xor(s[vv], m);
    }
    // select value (l&7) without runtime array index
    int lm = l & 7;
    float a0 = (lm & 1) ? s[1] : s[0];
    float a1 = (lm & 1) ? s[3] : s[2];
    float a2 = (lm & 1) ? s[5] : s[4];
    float a3 = (lm & 1) ? s[7] : s[6];
    float b0 = (lm & 2) ? a1 : a0;
    float b1 = (lm & 2) ? a3 : a2;
    float x = (lm & 4) ? b1 : b0;
    // phase 2: reduce across the 8 groups
    x += __shfl_xor(x, 8);
    x += __shfl_xor(x, 16);
    x += __shfl_xor(x, 32);
    // combine pitch (lanes 0..3) with dur (lanes 4..7)
    x += __shfl_xor(x, 4);
    if (l < 4) logits[l][j] += x;
    j = jn;
    p = pn;
    d4 = dn;
  }
  __syncthreads();

  // softmax: wave w handles head w; lane l handles j = 4l..4l+3
  int j0 = l * 4;
  float v0 = logits[w][j0 + 0], v1 = logits[w][j0 + 1];
  float v2 = logits[w][j0 + 2], v3 = logits[w][j0 + 3];
  if (mflag[j0 + 0] != 0.f) v0 = -9e15f;
  if (mflag[j0 + 1] != 0.f) v1 = -9e15f;
  if (mflag[j0 + 2] != 0.f) v2 = -9e15f;
  if (mflag[j0 + 3] != 0.f) v3 = -9e15f;
  float mx = fmaxf(fmaxf(v0, v1), fmaxf(v2, v3));
#pragma unroll
  for (int m = 1; m <= 32; m <<= 1) mx = fmaxf(mx, __shfl_xor(mx, m));
  float e0 = __expf(v0 - mx), e1 = __expf(v1 - mx);
  float e2 = __expf(v2 - mx), e3 = __expf(v3 - mx);
  float sm = e0 + e1 + e2 + e3;
#pragma unroll
  for (int m = 1; m <= 32; m <<= 1) sm += __shfl_xor(sm, m);
  float inv = 1.0f / sm;
  float4 rres = make_float4(e0 * inv, e1 * inv, e2 * inv, e3 * inv);
  *(float4*)(attn + (size_t)((b * 4 + w) * 256 + i) * 256 + j0) = rres;
}

// ---------------------------------------------------------------- B2: PV + fc epilogue
__global__ __launch_bounds__(256) void k_pv_fc(
    const float* __restrict__ attn, const float* __restrict__ vh,
    const float* __restrict__ fcT, const float* __restrict__ fcb,
    float* __restrict__ out) {
  int b = blockIdx.x >> 8, i = blockIdx.x & 255;
  int tid = threadIdx.x;
  int h = tid >> 6, l = tid & 63;

  __shared__ float arow[4][256];
  __shared__ float pre[256];

  *(float4*)&arow[h][4 * l] = *(const float4*)(attn + (size_t)((b * 4 + h) * 256 + i) * 256 + 4 * l);
  __syncthreads();

  float acc = 0.f;
  const float* vbase = vh + (size_t)(b * 4 + h) * 256 * 64 + l;
#pragma unroll 4
  for (int jj = 0; jj < 256; ++jj) acc += arow[h][jj] * vbase[(size_t)jj * 64];
  pre[tid] = acc;
  __syncthreads();

  float acc2 = fcb[tid];
#pragma unroll 4
  for (int c = 0; c < 256; ++c) acc2 += pre[c] * fcT[(size_t)c * 256 + tid];
  out[(size_t)(b * 256 + i) * 256 + tid] = acc2;
}

// ---------------------------------------------------------------- launcher
extern "C" void kernel_launch(void* const* d_in, const int* in_sizes, int n_in,
                              void* d_out, int out_size, void* d_ws, size_t ws_size,
                              hipStream_t stream) {
  (void)in_sizes; (void)n_in; (void)out_size; (void)ws_size;
  const float* q = (const float*)d_in[0];
  const float* k = (const float*)d_in[1];
  const float* v = (const float*)d_in[2];
  const float* amask = (const float*)d_in[3];
  const unsigned char* kpm = (const unsigned char*)d_in[4];
  const float* pitch = (const float*)d_in[5];
  const float* dur = (const float*)d_in[6];
  const float* Wq = (const float*)d_in[7];
  const float* Bq = (const float*)d_in[8];
  const float* Wk = (const float*)d_in[9];
  const float* Bk = (const float*)d_in[10];
  const float* Wv = (const float*)d_in[11];
  const float* Bv = (const float*)d_in[12];
  const float* fcw = (const float*)d_in[13];
  const float* fcb = (const float*)d_in[14];
  const float* prw = (const float*)d_in[15];
  const float* drw = (const float*)d_in[17];
  // pr_b (16) / dr_b (18) intentionally unused: j-constant logit offsets cancel in softmax.

  float* out = (float*)d_out;
  float* attn = out + 2 * 256 * 256;  // 131072

  float* wsf = (float*)d_ws;
  float* qh = wsf;              // 131072
  float* kh = qh + 131072;      // 131072
  float* vh = kh + 131072;      // 131072
  float* qpr = vh + 131072;     // 524288
  float* qdr = qpr + 524288;    // 524288
  float* fcT = qdr + 524288;    // 65536   (total ~6.03 MB)

  k_transpose<<<64, 256, 0, stream>>>(fcw, fcT);
  k_proj<<<96, 256, 0, stream>>>(q, k, v, Wq, Bq, Wk, Bk, Wv, Bv, qh, kh, vh);
  k_qprdr<<<256, 256, 0, stream>>>(qh, prw, drw, qpr, qdr);
  k_qk<<<128, 256, 0, stream>>>(qh, kh, attn);
  k_bias_softmax<<<512, 256, 0, stream>>>(pitch, dur, qpr, qdr, amask, kpm, attn);
  k_pv_fc<<<512, 256, 0, stream>>>(attn, vh, fcT, fcb, out);
}

// Round 2
// 118.785 us; speedup vs baseline: 1.0210x; 1.0210x over previous
//
#include <hip/hip_runtime.h>
#include <math.h>

// Problem constants: B=2, L=256, D=256, H=4, DH=64.
// Output tuple: out (B,L,D)=131072 floats, then attn (B,H,L,L)=524288 floats.
//
// Algebra:
//  - qh . (pitch_rel @ pr_w^T)  ==  pitch_rel . (qh @ pr_w_headslice)  -> precompute qpr.
//  - pr_b / dr_b are j-constant logit offsets -> cancel in softmax -> dropped.
//  - 1/sqrt(DH) folded into qh.
//  - bias[h,j] = P[j,:].qp[h,:] + Dr[j,:].qd[h,:] -> fuse both dots before the
//    cross-lane reduce (12 shuffles/j instead of 28).

// ---------------------------------------------------------------- A0: transpose fc_w
__global__ __launch_bounds__(256) void k_transpose(const float* __restrict__ in,
                                                   float* __restrict__ out) {
  __shared__ float t[32][33];
  int bx = blockIdx.x & 7, by = blockIdx.x >> 3;
  int x = threadIdx.x & 31, y0 = threadIdx.x >> 5;
#pragma unroll
  for (int yy = 0; yy < 32; yy += 8)
    t[yy + y0][x] = in[(size_t)(by * 32 + yy + y0) * 256 + bx * 32 + x];
  __syncthreads();
#pragma unroll
  for (int yy = 0; yy < 32; yy += 8)
    out[(size_t)(bx * 32 + yy + y0) * 256 + by * 32 + x] = t[x][yy + y0];
}

// ---------------------------------------------------------------- A1: q/k/v projections
__global__ __launch_bounds__(256) void k_proj(
    const float* __restrict__ q, const float* __restrict__ k_, const float* __restrict__ v,
    const float* __restrict__ Wq, const float* __restrict__ Bq,
    const float* __restrict__ Wk, const float* __restrict__ Bk,
    const float* __restrict__ Wv, const float* __restrict__ Bv,
    float* __restrict__ qh, float* __restrict__ kh, float* __restrict__ vh) {
  int blk = blockIdx.x;
  int m = blk >> 5;
  int r = blk & 31;
  int b = r >> 4, it = (r >> 2) & 3, ot = r & 3;
  const float* X = (m == 0) ? q : (m == 1) ? k_ : v;
  const float* W = (m == 0) ? Wq : (m == 1) ? Wk : Wv;
  const float* Bs = (m == 0) ? Bq : (m == 1) ? Bk : Bv;
  float* OUT = (m == 0) ? qh : (m == 1) ? kh : vh;
  const float scale = (m == 0) ? 0.125f : 1.0f;

  __shared__ float xs[64][33];
  __shared__ float ws[64][33];
  int tid = threadIdx.x;
  int ti = tid >> 4, to = tid & 15;
  int lr = tid >> 2, lc = (tid & 3) * 8;
  float acc[4][4] = {};

  for (int k0 = 0; k0 < 256; k0 += 32) {
    float4 a0 = *(const float4*)(X + (size_t)(b * 256 + it * 64 + lr) * 256 + k0 + lc);
    float4 a1 = *(const float4*)(X + (size_t)(b * 256 + it * 64 + lr) * 256 + k0 + lc + 4);
    xs[lr][lc + 0] = a0.x; xs[lr][lc + 1] = a0.y; xs[lr][lc + 2] = a0.z; xs[lr][lc + 3] = a0.w;
    xs[lr][lc + 4] = a1.x; xs[lr][lc + 5] = a1.y; xs[lr][lc + 6] = a1.z; xs[lr][lc + 7] = a1.w;
    float4 w0 = *(const float4*)(W + (size_t)(ot * 64 + lr) * 256 + k0 + lc);
    float4 w1 = *(const float4*)(W + (size_t)(ot * 64 + lr) * 256 + k0 + lc + 4);
    ws[lr][lc + 0] = w0.x; ws[lr][lc + 1] = w0.y; ws[lr][lc + 2] = w0.z; ws[lr][lc + 3] = w0.w;
    ws[lr][lc + 4] = w1.x; ws[lr][lc + 5] = w1.y; ws[lr][lc + 6] = w1.z; ws[lr][lc + 7] = w1.w;
    __syncthreads();
#pragma unroll
    for (int kk = 0; kk < 32; ++kk) {
      float xv0 = xs[ti * 4 + 0][kk], xv1 = xs[ti * 4 + 1][kk];
      float xv2 = xs[ti * 4 + 2][kk], xv3 = xs[ti * 4 + 3][kk];
      float wv0 = ws[0 * 16 + to][kk], wv1 = ws[1 * 16 + to][kk];
      float wv2 = ws[2 * 16 + to][kk], wv3 = ws[3 * 16 + to][kk];
      acc[0][0] += xv0 * wv0; acc[0][1] += xv0 * wv1; acc[0][2] += xv0 * wv2; acc[0][3] += xv0 * wv3;
      acc[1][0] += xv1 * wv0; acc[1][1] += xv1 * wv1; acc[1][2] += xv1 * wv2; acc[1][3] += xv1 * wv3;
      acc[2][0] += xv2 * wv0; acc[2][1] += xv2 * wv1; acc[2][2] += xv2 * wv2; acc[2][3] += xv2 * wv3;
      acc[3][0] += xv3 * wv0; acc[3][1] += xv3 * wv1; acc[3][2] += xv3 * wv2; acc[3][3] += xv3 * wv3;
    }
    __syncthreads();
  }
#pragma unroll
  for (int ii = 0; ii < 4; ++ii)
#pragma unroll
    for (int oo = 0; oo < 4; ++oo) {
      int i = it * 64 + ti * 4 + ii;
      int dd = oo * 16 + to;
      OUT[(size_t)((b * 4 + ot) * 256 + i) * 64 + dd] = (acc[ii][oo] + Bs[ot * 64 + dd]) * scale;
    }
}

// ---------------------------------------------------------------- A2: qpr / qdr
__global__ __launch_bounds__(256) void k_qprdr(
    const float* __restrict__ qh, const float* __restrict__ prw,
    const float* __restrict__ drw, float* __restrict__ qpr, float* __restrict__ qdr) {
  int blk = blockIdx.x;  // t*128 + rt*4 + et
  int t = blk >> 7;
  int r2 = blk & 127;
  int rt = r2 >> 2, et = r2 & 3;
  const float* W = t ? drw : prw;
  float* OUT = t ? qdr : qpr;
  int h = (rt >> 2) & 3;

  __shared__ float xs[64][33];
  __shared__ float ws2[32][64];
  int tid = threadIdx.x;
  int ti = tid >> 4, to = tid & 15;
  float acc[4][4] = {};

  for (int k0 = 0; k0 < 64; k0 += 32) {
    int lr = tid >> 2, lc = (tid & 3) * 8;
    float4 a0 = *(const float4*)(qh + (size_t)(rt * 64 + lr) * 64 + k0 + lc);
    float4 a1 = *(const float4*)(qh + (size_t)(rt * 64 + lr) * 64 + k0 + lc + 4);
    xs[lr][lc + 0] = a0.x; xs[lr][lc + 1] = a0.y; xs[lr][lc + 2] = a0.z; xs[lr][lc + 3] = a0.w;
    xs[lr][lc + 4] = a1.x; xs[lr][lc + 5] = a1.y; xs[lr][lc + 6] = a1.z; xs[lr][lc + 7] = a1.w;
    int wr = tid >> 3, wc = (tid & 7) * 8;
    float4 w0 = *(const float4*)(W + (size_t)(h * 64 + k0 + wr) * 256 + et * 64 + wc);
    float4 w1 = *(const float4*)(W + (size_t)(h * 64 + k0 + wr) * 256 + et * 64 + wc + 4);
    ws2[wr][wc + 0] = w0.x; ws2[wr][wc + 1] = w0.y; ws2[wr][wc + 2] = w0.z; ws2[wr][wc + 3] = w0.w;
    ws2[wr][wc + 4] = w1.x; ws2[wr][wc + 5] = w1.y; ws2[wr][wc + 6] = w1.z; ws2[wr][wc + 7] = w1.w;
    __syncthreads();
#pragma unroll
    for (int kk = 0; kk < 32; ++kk) {
      float xv0 = xs[ti * 4 + 0][kk], xv1 = xs[ti * 4 + 1][kk];
      float xv2 = xs[ti * 4 + 2][kk], xv3 = xs[ti * 4 + 3][kk];
      float wv0 = ws2[kk][0 * 16 + to], wv1 = ws2[kk][1 * 16 + to];
      float wv2 = ws2[kk][2 * 16 + to], wv3 = ws2[kk][3 * 16 + to];
      acc[0][0] += xv0 * wv0; acc[0][1] += xv0 * wv1; acc[0][2] += xv0 * wv2; acc[0][3] += xv0 * wv3;
      acc[1][0] += xv1 * wv0; acc[1][1] += xv1 * wv1; acc[1][2] += xv1 * wv2; acc[1][3] += xv1 * wv3;
      acc[2][0] += xv2 * wv0; acc[2][1] += xv2 * wv1; acc[2][2] += xv2 * wv2; acc[2][3] += xv2 * wv3;
      acc[3][0] += xv3 * wv0; acc[3][1] += xv3 * wv1; acc[3][2] += xv3 * wv2; acc[3][3] += xv3 * wv3;
    }
    __syncthreads();
  }
#pragma unroll
  for (int ii = 0; ii < 4; ++ii)
#pragma unroll
    for (int oo = 0; oo < 4; ++oo)
      OUT[(size_t)(rt * 64 + ti * 4 + ii) * 256 + et * 64 + oo * 16 + to] = acc[ii][oo];
}

// ---------------------------------------------------------------- A3: content logits qk
__global__ __launch_bounds__(256) void k_qk(const float* __restrict__ qh,
                                            const float* __restrict__ kh,
                                            float* __restrict__ qk) {
  int blk = blockIdx.x;  // bh*16 + it*4 + jt
  int bh = blk >> 4, it = (blk >> 2) & 3, jt = blk & 3;
  __shared__ float xs[64][33];
  __shared__ float ys[64][33];
  int tid = threadIdx.x;
  int ti = tid >> 4, to = tid & 15;
  float acc[4][4] = {};

  for (int k0 = 0; k0 < 64; k0 += 32) {
    int lr = tid >> 2, lc = (tid & 3) * 8;
    float4 a0 = *(const float4*)(qh + (size_t)(bh * 256 + it * 64 + lr) * 64 + k0 + lc);
    float4 a1 = *(const float4*)(qh + (size_t)(bh * 256 + it * 64 + lr) * 64 + k0 + lc + 4);
    xs[lr][lc + 0] = a0.x; xs[lr][lc + 1] = a0.y; xs[lr][lc + 2] = a0.z; xs[lr][lc + 3] = a0.w;
    xs[lr][lc + 4] = a1.x; xs[lr][lc + 5] = a1.y; xs[lr][lc + 6] = a1.z; xs[lr][lc + 7] = a1.w;
    float4 b0 = *(const float4*)(kh + (size_t)(bh * 256 + jt * 64 + lr) * 64 + k0 + lc);
    float4 b1 = *(const float4*)(kh + (size_t)(bh * 256 + jt * 64 + lr) * 64 + k0 + lc + 4);
    ys[lr][lc + 0] = b0.x; ys[lr][lc + 1] = b0.y; ys[lr][lc + 2] = b0.z; ys[lr][lc + 3] = b0.w;
    ys[lr][lc + 4] = b1.x; ys[lr][lc + 5] = b1.y; ys[lr][lc + 6] = b1.z; ys[lr][lc + 7] = b1.w;
    __syncthreads();
#pragma unroll
    for (int kk = 0; kk < 32; ++kk) {
      float xv0 = xs[ti * 4 + 0][kk], xv1 = xs[ti * 4 + 1][kk];
      float xv2 = xs[ti * 4 + 2][kk], xv3 = xs[ti * 4 + 3][kk];
      float wv0 = ys[0 * 16 + to][kk], wv1 = ys[1 * 16 + to][kk];
      float wv2 = ys[2 * 16 + to][kk], wv3 = ys[3 * 16 + to][kk];
      acc[0][0] += xv0 * wv0; acc[0][1] += xv0 * wv1; acc[0][2] += xv0 * wv2; acc[0][3] += xv0 * wv3;
      acc[1][0] += xv1 * wv0; acc[1][1] += xv1 * wv1; acc[1][2] += xv1 * wv2; acc[1][3] += xv1 * wv3;
      acc[2][0] += xv2 * wv0; acc[2][1] += xv2 * wv1; acc[2][2] += xv2 * wv2; acc[2][3] += xv2 * wv3;
      acc[3][0] += xv3 * wv0; acc[3][1] += xv3 * wv1; acc[3][2] += xv3 * wv2; acc[3][3] += xv3 * wv3;
    }
    __syncthreads();
  }
#pragma unroll
  for (int ii = 0; ii < 4; ++ii)
#pragma unroll
    for (int jj = 0; jj < 4; ++jj)
      qk[(size_t)(bh * 256 + it * 64 + ti * 4 + ii) * 256 + jt * 64 + jj * 16 + to] = acc[ii][jj];
}

// ---------------------------------------------------------------- B1: bias stream (HOT)
// Block = (b, i, jc): 64 j's of the pitch/dur rows for one (b,i). Wave w handles
// j = jc*64 + w + 4t; lane l owns e-slice 4l..4l+3 of qpr/qdr. Writes masked
// logits (qk + bias) into attn buffer; softmax is a separate pass.
__global__ __launch_bounds__(256) void k_bias(
    const float* __restrict__ pitch, const float* __restrict__ dur,
    const float* __restrict__ qpr, const float* __restrict__ qdr,
    const float* __restrict__ amask, const unsigned char* __restrict__ kpm,
    float* __restrict__ attn) {
  int blk = blockIdx.x;            // ((b*256 + i)*4 + jc)
  int jc = blk & 3;
  int bi = blk >> 2;
  int b = bi >> 8, i = bi & 255;
  int tid = threadIdx.x, w = tid >> 6, l = tid & 63;

  __shared__ float bias_s[4][64];

  // per-lane state for the epilogue: this wave writes head w, j = jc*64 + l
  size_t rowbase = (size_t)((b * 4 + w) * 256 + i) * 256 + jc * 64;
  float qkreg = attn[rowbase + l];
  bool maskreg = (kpm[b * 256 + i] != 0) || (amask[(size_t)i * 256 + jc * 64 + l] != 0.f);

  float4 qp[4], qd[4];
#pragma unroll
  for (int h = 0; h < 4; ++h) {
    qp[h] = *(const float4*)(qpr + (size_t)((b * 4 + h) * 256 + i) * 256 + 4 * l);
    qd[h] = *(const float4*)(qdr + (size_t)((b * 4 + h) * 256 + i) * 256 + 4 * l);
  }

  const float4* pbase = (const float4*)(pitch + (size_t)(b * 256 + i) * 65536);
  const float4* dbase = (const float4*)(dur + (size_t)(b * 256 + i) * 65536);

  int j = jc * 64 + w;
  float4 p = pbase[(size_t)j * 64 + l];
  float4 d4 = dbase[(size_t)j * 64 + l];
#pragma unroll 4
  for (int t = 0; t < 16; ++t) {
    float4 pn = make_float4(0.f, 0.f, 0.f, 0.f);
    float4 dn = make_float4(0.f, 0.f, 0.f, 0.f);
    if (t < 15) {  // one-ahead prefetch
      pn = pbase[(size_t)(j + 4) * 64 + l];
      dn = dbase[(size_t)(j + 4) * 64 + l];
    }
    // fused pitch+dur dot per head (bias[h,j] = P.qp[h] + D.qd[h])
    float s0 = p.x * qp[0].x + p.y * qp[0].y + p.z * qp[0].z + p.w * qp[0].w
             + d4.x * qd[0].x + d4.y * qd[0].y + d4.z * qd[0].z + d4.w * qd[0].w;
    float s1 = p.x * qp[1].x + p.y * qp[1].y + p.z * qp[1].z + p.w * qp[1].w
             + d4.x * qd[1].x + d4.y * qd[1].y + d4.z * qd[1].z + d4.w * qd[1].w;
    float s2 = p.x * qp[2].x + p.y * qp[2].y + p.z * qp[2].z + p.w * qp[2].w
             + d4.x * qd[2].x + d4.y * qd[2].y + d4.z * qd[2].z + d4.w * qd[2].w;
    float s3 = p.x * qp[3].x + p.y * qp[3].y + p.z * qp[3].z + p.w * qp[3].w
             + d4.x * qd[3].x + d4.y * qd[3].y + d4.z * qd[3].z + d4.w * qd[3].w;
    // reduce 4 values within 4-lane groups (masks 1,2)
    s0 += __shfl_xor(s0, 1); s1 += __shfl_xor(s1, 1);
    s2 += __shfl_xor(s2, 1); s3 += __shfl_xor(s3, 1);
    s0 += __shfl_xor(s0, 2); s1 += __shfl_xor(s1, 2);
    s2 += __shfl_xor(s2, 2); s3 += __shfl_xor(s3, 2);
    // lane selects its head's partial (lm = l&3)
    int lm = l & 3;
    float a0 = (lm & 1) ? s1 : s0;
    float a1 = (lm & 1) ? s3 : s2;
    float x = (lm & 2) ? a1 : a0;
    // reduce across the 16 groups
    x += __shfl_xor(x, 4);
    x += __shfl_xor(x, 8);
    x += __shfl_xor(x, 16);
    x += __shfl_xor(x, 32);
    if (l < 4) bias_s[l][(j & 63)] = x;
    j += 4;
    p = pn;
    d4 = dn;
  }
  __syncthreads();

  float val = qkreg + bias_s[w][l];
  if (maskreg) val = -9e15f;
  attn[rowbase + l] = val;
}

// ---------------------------------------------------------------- B2: softmax rows
__global__ __launch_bounds__(256) void k_softmax(float* __restrict__ attn) {
  int r = blockIdx.x * 4 + (threadIdx.x >> 6);  // row in [0, 2048)
  int l = threadIdx.x & 63;
  float* row = attn + (size_t)r * 256;
  float4 v = *(float4*)(row + 4 * l);
  float mx = fmaxf(fmaxf(v.x, v.y), fmaxf(v.z, v.w));
#pragma unroll
  for (int m = 1; m <= 32; m <<= 1) mx = fmaxf(mx, __shfl_xor(mx, m));
  float e0 = __expf(v.x - mx), e1 = __expf(v.y - mx);
  float e2 = __expf(v.z - mx), e3 = __expf(v.w - mx);
  float sm = e0 + e1 + e2 + e3;
#pragma unroll
  for (int m = 1; m <= 32; m <<= 1) sm += __shfl_xor(sm, m);
  float inv = 1.0f / sm;
  *(float4*)(row + 4 * l) = make_float4(e0 * inv, e1 * inv, e2 * inv, e3 * inv);
}

// ---------------------------------------------------------------- B3: PV + fc epilogue
__global__ __launch_bounds__(256) void k_pv_fc(
    const float* __restrict__ attn, const float* __restrict__ vh,
    const float* __restrict__ fcT, const float* __restrict__ fcb,
    float* __restrict__ out) {
  int b = blockIdx.x >> 8, i = blockIdx.x & 255;
  int tid = threadIdx.x;
  int h = tid >> 6, l = tid & 63;

  __shared__ float arow[4][256];
  __shared__ float pre[256];

  *(float4*)&arow[h][4 * l] = *(const float4*)(attn + (size_t)((b * 4 + h) * 256 + i) * 256 + 4 * l);
  __syncthreads();

  float acc = 0.f;
  const float* vbase = vh + (size_t)(b * 4 + h) * 256 * 64 + l;
#pragma unroll 4
  for (int jj = 0; jj < 256; ++jj) acc += arow[h][jj] * vbase[(size_t)jj * 64];
  pre[tid] = acc;
  __syncthreads();

  float acc2 = fcb[tid];
#pragma unroll 4
  for (int c = 0; c < 256; ++c) acc2 += pre[c] * fcT[(size_t)c * 256 + tid];
  out[(size_t)(b * 256 + i) * 256 + tid] = acc2;
}

// ---------------------------------------------------------------- launcher
extern "C" void kernel_launch(void* const* d_in, const int* in_sizes, int n_in,
                              void* d_out, int out_size, void* d_ws, size_t ws_size,
                              hipStream_t stream) {
  (void)in_sizes; (void)n_in; (void)out_size; (void)ws_size;
  const float* q = (const float*)d_in[0];
  const float* k = (const float*)d_in[1];
  const float* v = (const float*)d_in[2];
  const float* amask = (const float*)d_in[3];
  const unsigned char* kpm = (const unsigned char*)d_in[4];
  const float* pitch = (const float*)d_in[5];
  const float* dur = (const float*)d_in[6];
  const float* Wq = (const float*)d_in[7];
  const float* Bq = (const float*)d_in[8];
  const float* Wk = (const float*)d_in[9];
  const float* Bk = (const float*)d_in[10];
  const float* Wv = (const float*)d_in[11];
  const float* Bv = (const float*)d_in[12];
  const float* fcw = (const float*)d_in[13];
  const float* fcb = (const float*)d_in[14];
  const float* prw = (const float*)d_in[15];
  const float* drw = (const float*)d_in[17];
  // pr_b (16) / dr_b (18) intentionally unused: j-constant logit offsets cancel in softmax.

  float* out = (float*)d_out;
  float* attn = out + 2 * 256 * 256;  // 131072

  float* wsf = (float*)d_ws;
  float* qh = wsf;              // 131072
  float* kh = qh + 131072;      // 131072
  float* vh = kh + 131072;      // 131072
  float* qpr = vh + 131072;     // 524288
  float* qdr = qpr + 524288;    // 524288
  float* fcT = qdr + 524288;    // 65536   (total ~6.03 MB)

  k_transpose<<<64, 256, 0, stream>>>(fcw, fcT);
  k_proj<<<96, 256, 0, stream>>>(q, k, v, Wq, Bq, Wk, Bk, Wv, Bv, qh, kh, vh);
  k_qprdr<<<256, 256, 0, stream>>>(qh, prw, drw, qpr, qdr);
  k_qk<<<128, 256, 0, stream>>>(qh, kh, attn);
  k_bias<<<2048, 256, 0, stream>>>(pitch, dur, qpr, qdr, amask, kpm, attn);
  k_softmax<<<512, 256, 0, stream>>>(attn);
  k_pv_fc<<<512, 256, 0, stream>>>(attn, vh, fcT, fcb, out);
}

// Round 3
// 116.983 us; speedup vs baseline: 1.0367x; 1.0154x over previous
//
#include <hip/hip_runtime.h>
#include <math.h>

// Problem constants: B=2, L=256, D=256, H=4, DH=64.
// Output tuple: out (B,L,D)=131072 floats, then attn (B,H,L,L)=524288 floats.
//
// Algebra:
//  - qh . (pitch_rel @ pr_w^T)  ==  pitch_rel . (qh @ pr_w_headslice)  -> precompute qpr.
//  - pr_b / dr_b are j-constant logit offsets -> cancel in softmax -> dropped.
//  - 1/sqrt(DH) folded into qh.
//  - k_bias v3: register accumulators acc[8j][4h] per wave, 16 loads in flight
//    (MLP fix for the latency-bound R2 version), LDS-transpose reduce at end.

// ---------------------------------------------------------------- A0: transpose fc_w
__global__ __launch_bounds__(256) void k_transpose(const float* __restrict__ in,
                                                   float* __restrict__ out) {
  __shared__ float t[32][33];
  int bx = blockIdx.x & 7, by = blockIdx.x >> 3;
  int x = threadIdx.x & 31, y0 = threadIdx.x >> 5;
#pragma unroll
  for (int yy = 0; yy < 32; yy += 8)
    t[yy + y0][x] = in[(size_t)(by * 32 + yy + y0) * 256 + bx * 32 + x];
  __syncthreads();
#pragma unroll
  for (int yy = 0; yy < 32; yy += 8)
    out[(size_t)(bx * 32 + yy + y0) * 256 + by * 32 + x] = t[x][yy + y0];
}

// ---------------------------------------------------------------- A1: q/k/v projections
__global__ __launch_bounds__(256) void k_proj(
    const float* __restrict__ q, const float* __restrict__ k_, const float* __restrict__ v,
    const float* __restrict__ Wq, const float* __restrict__ Bq,
    const float* __restrict__ Wk, const float* __restrict__ Bk,
    const float* __restrict__ Wv, const float* __restrict__ Bv,
    float* __restrict__ qh, float* __restrict__ kh, float* __restrict__ vh) {
  int blk = blockIdx.x;
  int m = blk >> 5;
  int r = blk & 31;
  int b = r >> 4, it = (r >> 2) & 3, ot = r & 3;
  const float* X = (m == 0) ? q : (m == 1) ? k_ : v;
  const float* W = (m == 0) ? Wq : (m == 1) ? Wk : Wv;
  const float* Bs = (m == 0) ? Bq : (m == 1) ? Bk : Bv;
  float* OUT = (m == 0) ? qh : (m == 1) ? kh : vh;
  const float scale = (m == 0) ? 0.125f : 1.0f;

  __shared__ float xs[64][33];
  __shared__ float ws[64][33];
  int tid = threadIdx.x;
  int ti = tid >> 4, to = tid & 15;
  int lr = tid >> 2, lc = (tid & 3) * 8;
  float acc[4][4] = {};

  for (int k0 = 0; k0 < 256; k0 += 32) {
    float4 a0 = *(const float4*)(X + (size_t)(b * 256 + it * 64 + lr) * 256 + k0 + lc);
    float4 a1 = *(const float4*)(X + (size_t)(b * 256 + it * 64 + lr) * 256 + k0 + lc + 4);
    xs[lr][lc + 0] = a0.x; xs[lr][lc + 1] = a0.y; xs[lr][lc + 2] = a0.z; xs[lr][lc + 3] = a0.w;
    xs[lr][lc + 4] = a1.x; xs[lr][lc + 5] = a1.y; xs[lr][lc + 6] = a1.z; xs[lr][lc + 7] = a1.w;
    float4 w0 = *(const float4*)(W + (size_t)(ot * 64 + lr) * 256 + k0 + lc);
    float4 w1 = *(const float4*)(W + (size_t)(ot * 64 + lr) * 256 + k0 + lc + 4);
    ws[lr][lc + 0] = w0.x; ws[lr][lc + 1] = w0.y; ws[lr][lc + 2] = w0.z; ws[lr][lc + 3] = w0.w;
    ws[lr][lc + 4] = w1.x; ws[lr][lc + 5] = w1.y; ws[lr][lc + 6] = w1.z; ws[lr][lc + 7] = w1.w;
    __syncthreads();
#pragma unroll
    for (int kk = 0; kk < 32; ++kk) {
      float xv0 = xs[ti * 4 + 0][kk], xv1 = xs[ti * 4 + 1][kk];
      float xv2 = xs[ti * 4 + 2][kk], xv3 = xs[ti * 4 + 3][kk];
      float wv0 = ws[0 * 16 + to][kk], wv1 = ws[1 * 16 + to][kk];
      float wv2 = ws[2 * 16 + to][kk], wv3 = ws[3 * 16 + to][kk];
      acc[0][0] += xv0 * wv0; acc[0][1] += xv0 * wv1; acc[0][2] += xv0 * wv2; acc[0][3] += xv0 * wv3;
      acc[1][0] += xv1 * wv0; acc[1][1] += xv1 * wv1; acc[1][2] += xv1 * wv2; acc[1][3] += xv1 * wv3;
      acc[2][0] += xv2 * wv0; acc[2][1] += xv2 * wv1; acc[2][2] += xv2 * wv2; acc[2][3] += xv2 * wv3;
      acc[3][0] += xv3 * wv0; acc[3][1] += xv3 * wv1; acc[3][2] += xv3 * wv2; acc[3][3] += xv3 * wv3;
    }
    __syncthreads();
  }
#pragma unroll
  for (int ii = 0; ii < 4; ++ii)
#pragma unroll
    for (int oo = 0; oo < 4; ++oo) {
      int i = it * 64 + ti * 4 + ii;
      int dd = oo * 16 + to;
      OUT[(size_t)((b * 4 + ot) * 256 + i) * 64 + dd] = (acc[ii][oo] + Bs[ot * 64 + dd]) * scale;
    }
}

// ---------------------------------------------------------------- A2: qpr / qdr
__global__ __launch_bounds__(256) void k_qprdr(
    const float* __restrict__ qh, const float* __restrict__ prw,
    const float* __restrict__ drw, float* __restrict__ qpr, float* __restrict__ qdr) {
  int blk = blockIdx.x;  // t*128 + rt*4 + et
  int t = blk >> 7;
  int r2 = blk & 127;
  int rt = r2 >> 2, et = r2 & 3;
  const float* W = t ? drw : prw;
  float* OUT = t ? qdr : qpr;
  int h = (rt >> 2) & 3;

  __shared__ float xs[64][33];
  __shared__ float ws2[32][64];
  int tid = threadIdx.x;
  int ti = tid >> 4, to = tid & 15;
  float acc[4][4] = {};

  for (int k0 = 0; k0 < 64; k0 += 32) {
    int lr = tid >> 2, lc = (tid & 3) * 8;
    float4 a0 = *(const float4*)(qh + (size_t)(rt * 64 + lr) * 64 + k0 + lc);
    float4 a1 = *(const float4*)(qh + (size_t)(rt * 64 + lr) * 64 + k0 + lc + 4);
    xs[lr][lc + 0] = a0.x; xs[lr][lc + 1] = a0.y; xs[lr][lc + 2] = a0.z; xs[lr][lc + 3] = a0.w;
    xs[lr][lc + 4] = a1.x; xs[lr][lc + 5] = a1.y; xs[lr][lc + 6] = a1.z; xs[lr][lc + 7] = a1.w;
    int wr = tid >> 3, wc = (tid & 7) * 8;
    float4 w0 = *(const float4*)(W + (size_t)(h * 64 + k0 + wr) * 256 + et * 64 + wc);
    float4 w1 = *(const float4*)(W + (size_t)(h * 64 + k0 + wr) * 256 + et * 64 + wc + 4);
    ws2[wr][wc + 0] = w0.x; ws2[wr][wc + 1] = w0.y; ws2[wr][wc + 2] = w0.z; ws2[wr][wc + 3] = w0.w;
    ws2[wr][wc + 4] = w1.x; ws2[wr][wc + 5] = w1.y; ws2[wr][wc + 6] = w1.z; ws2[wr][wc + 7] = w1.w;
    __syncthreads();
#pragma unroll
    for (int kk = 0; kk < 32; ++kk) {
      float xv0 = xs[ti * 4 + 0][kk], xv1 = xs[ti * 4 + 1][kk];
      float xv2 = xs[ti * 4 + 2][kk], xv3 = xs[ti * 4 + 3][kk];
      float wv0 = ws2[kk][0 * 16 + to], wv1 = ws2[kk][1 * 16 + to];
      float wv2 = ws2[kk][2 * 16 + to], wv3 = ws2[kk][3 * 16 + to];
      acc[0][0] += xv0 * wv0; acc[0][1] += xv0 * wv1; acc[0][2] += xv0 * wv2; acc[0][3] += xv0 * wv3;
      acc[1][0] += xv1 * wv0; acc[1][1] += xv1 * wv1; acc[1][2] += xv1 * wv2; acc[1][3] += xv1 * wv3;
      acc[2][0] += xv2 * wv0; acc[2][1] += xv2 * wv1; acc[2][2] += xv2 * wv2; acc[2][3] += xv2 * wv3;
      acc[3][0] += xv3 * wv0; acc[3][1] += xv3 * wv1; acc[3][2] += xv3 * wv2; acc[3][3] += xv3 * wv3;
    }
    __syncthreads();
  }
#pragma unroll
  for (int ii = 0; ii < 4; ++ii)
#pragma unroll
    for (int oo = 0; oo < 4; ++oo)
      OUT[(size_t)(rt * 64 + ti * 4 + ii) * 256 + et * 64 + oo * 16 + to] = acc[ii][oo];
}

// ---------------------------------------------------------------- A3: content logits qk
__global__ __launch_bounds__(256) void k_qk(const float* __restrict__ qh,
                                            const float* __restrict__ kh,
                                            float* __restrict__ qk) {
  int blk = blockIdx.x;  // bh*16 + it*4 + jt
  int bh = blk >> 4, it = (blk >> 2) & 3, jt = blk & 3;
  __shared__ float xs[64][33];
  __shared__ float ys[64][33];
  int tid = threadIdx.x;
  int ti = tid >> 4, to = tid & 15;
  float acc[4][4] = {};

  for (int k0 = 0; k0 < 64; k0 += 32) {
    int lr = tid >> 2, lc = (tid & 3) * 8;
    float4 a0 = *(const float4*)(qh + (size_t)(bh * 256 + it * 64 + lr) * 64 + k0 + lc);
    float4 a1 = *(const float4*)(qh + (size_t)(bh * 256 + it * 64 + lr) * 64 + k0 + lc + 4);
    xs[lr][lc + 0] = a0.x; xs[lr][lc + 1] = a0.y; xs[lr][lc + 2] = a0.z; xs[lr][lc + 3] = a0.w;
    xs[lr][lc + 4] = a1.x; xs[lr][lc + 5] = a1.y; xs[lr][lc + 6] = a1.z; xs[lr][lc + 7] = a1.w;
    float4 b0 = *(const float4*)(kh + (size_t)(bh * 256 + jt * 64 + lr) * 64 + k0 + lc);
    float4 b1 = *(const float4*)(kh + (size_t)(bh * 256 + jt * 64 + lr) * 64 + k0 + lc + 4);
    ys[lr][lc + 0] = b0.x; ys[lr][lc + 1] = b0.y; ys[lr][lc + 2] = b0.z; ys[lr][lc + 3] = b0.w;
    ys[lr][lc + 4] = b1.x; ys[lr][lc + 5] = b1.y; ys[lr][lc + 6] = b1.z; ys[lr][lc + 7] = b1.w;
    __syncthreads();
#pragma unroll
    for (int kk = 0; kk < 32; ++kk) {
      float xv0 = xs[ti * 4 + 0][kk], xv1 = xs[ti * 4 + 1][kk];
      float xv2 = xs[ti * 4 + 2][kk], xv3 = xs[ti * 4 + 3][kk];
      float wv0 = ys[0 * 16 + to][kk], wv1 = ys[1 * 16 + to][kk];
      float wv2 = ys[2 * 16 + to][kk], wv3 = ys[3 * 16 + to][kk];
      acc[0][0] += xv0 * wv0; acc[0][1] += xv0 * wv1; acc[0][2] += xv0 * wv2; acc[0][3] += xv0 * wv3;
      acc[1][0] += xv1 * wv0; acc[1][1] += xv1 * wv1; acc[1][2] += xv1 * wv2; acc[1][3] += xv1 * wv3;
      acc[2][0] += xv2 * wv0; acc[2][1] += xv2 * wv1; acc[2][2] += xv2 * wv2; acc[2][3] += xv2 * wv3;
      acc[3][0] += xv3 * wv0; acc[3][1] += xv3 * wv1; acc[3][2] += xv3 * wv2; acc[3][3] += xv3 * wv3;
    }
    __syncthreads();
  }
#pragma unroll
  for (int ii = 0; ii < 4; ++ii)
#pragma unroll
    for (int jj = 0; jj < 4; ++jj)
      qk[(size_t)(bh * 256 + it * 64 + ti * 4 + ii) * 256 + jt * 64 + jj * 16 + to] = acc[ii][jj];
}

// ---------------------------------------------------------------- B1: bias stream (HOT, v3)
// Block = (b, i, jc) with jc one of 8 chunks of 32 j. Wave w owns j in
// jb..jb+7 (jb = jc*32 + w*8). Lane l owns e-slice 4l..4l+3. 16 independent
// float4 loads in flight per wave; acc[8][4] in registers; LDS-transpose
// reduce (pad-65, conflict-free, per-wave region -> no block barrier).
__global__ __launch_bounds__(256, 3) void k_bias(
    const float* __restrict__ pitch, const float* __restrict__ dur,
    const float* __restrict__ qpr, const float* __restrict__ qdr,
    const float* __restrict__ amask, const unsigned char* __restrict__ kpm,
    float* __restrict__ attn) {
  int blk = blockIdx.x;            // ((b*256 + i)*8 + jc)
  int jc = blk & 7;
  int bi = blk >> 3;
  int b = bi >> 8, i = bi & 255;
  int tid = threadIdx.x, w = tid >> 6, l = tid & 63;
  int jb = jc * 32 + w * 8;

  __shared__ float red[4][8][4][65];  // 33.3 KB

  // qp/qd fragments (e-slice 4l..4l+3) for all 4 heads
  float4 qp[4], qd[4];
#pragma unroll
  for (int h = 0; h < 4; ++h) {
    qp[h] = *(const float4*)(qpr + (size_t)((b * 4 + h) * 256 + i) * 256 + 4 * l);
    qd[h] = *(const float4*)(qdr + (size_t)((b * 4 + h) * 256 + i) * 256 + 4 * l);
  }

  // epilogue per-lane output assignment: p = l&31 -> (jj,h) = (p>>2, p&3)
  int p = l & 31;
  int jj_o = p >> 2, h_o = p & 3;
  int jabs = jb + jj_o;
  size_t orow = (size_t)((b * 4 + h_o) * 256 + i) * 256 + jabs;
  float qkreg = attn[orow];
  bool maskreg = (kpm[b * 256 + i] != 0) || (amask[(size_t)i * 256 + jabs] != 0.f);

  const float4* prow = (const float4*)(pitch + ((size_t)(b * 256 + i) * 256 + jb) * 256);
  const float4* drow = (const float4*)(dur + ((size_t)(b * 256 + i) * 256 + jb) * 256);

  // 16 independent loads in flight
  float4 P[8], D[8];
#pragma unroll
  for (int g = 0; g < 8; ++g) P[g] = prow[(size_t)g * 64 + l];
#pragma unroll
  for (int g = 0; g < 8; ++g) D[g] = drow[(size_t)g * 64 + l];

  float acc[8][4];
#pragma unroll
  for (int jj = 0; jj < 8; ++jj)
#pragma unroll
    for (int h = 0; h < 4; ++h)
      acc[jj][h] = P[jj].x * qp[h].x + P[jj].y * qp[h].y + P[jj].z * qp[h].z + P[jj].w * qp[h].w
                 + D[jj].x * qd[h].x + D[jj].y * qd[h].y + D[jj].z * qd[h].z + D[jj].w * qd[h].w;

  // transpose partials through LDS (per-wave region; within-wave RAW handled by lgkmcnt)
#pragma unroll
  for (int jj = 0; jj < 8; ++jj)
#pragma unroll
    for (int h = 0; h < 4; ++h)
      red[w][jj][h][l] = acc[jj][h];

  // lane l: sums half of row (jj_o, h_o); partner lane (l^32) sums the other half
  int half = l >> 5;
  const float* rrow = &red[w][jj_o][h_o][0];
  float x = 0.f;
#pragma unroll
  for (int c = 0; c < 32; ++c) x += rrow[half * 32 + c];
  x += __shfl_xor(x, 32);

  if (l < 32) {
    float val = qkreg + x;
    if (maskreg) val = -9e15f;
    attn[orow] = val;
  }
}

// ---------------------------------------------------------------- B2: softmax + PV + fc
__global__ __launch_bounds__(256) void k_pv_fc(
    float* __restrict__ attn, const float* __restrict__ vh,
    const float* __restrict__ fcT, const float* __restrict__ fcb,
    float* __restrict__ out) {
  int b = blockIdx.x >> 8, i = blockIdx.x & 255;
  int tid = threadIdx.x;
  int h = tid >> 6, l = tid & 63;

  __shared__ float arow[4][256];
  __shared__ float pre[256];

  // fused softmax: wave h owns row (b,h,i)
  float* rowp = attn + (size_t)((b * 4 + h) * 256 + i) * 256;
  float4 v4 = *(float4*)(rowp + 4 * l);
  float mx = fmaxf(fmaxf(v4.x, v4.y), fmaxf(v4.z, v4.w));
#pragma unroll
  for (int m = 1; m <= 32; m <<= 1) mx = fmaxf(mx, __shfl_xor(mx, m));
  float e0 = __expf(v4.x - mx), e1 = __expf(v4.y - mx);
  float e2 = __expf(v4.z - mx), e3 = __expf(v4.w - mx);
  float sm = e0 + e1 + e2 + e3;
#pragma unroll
  for (int m = 1; m <= 32; m <<= 1) sm += __shfl_xor(sm, m);
  float inv = 1.0f / sm;
  float4 a4 = make_float4(e0 * inv, e1 * inv, e2 * inv, e3 * inv);
  *(float4*)(rowp + 4 * l) = a4;
  *(float4*)&arow[h][4 * l] = a4;
  __syncthreads();

  float acc = 0.f;
  const float* vbase = vh + (size_t)(b * 4 + h) * 256 * 64 + l;
#pragma unroll 4
  for (int jj = 0; jj < 256; ++jj) acc += arow[h][jj] * vbase[(size_t)jj * 64];
  pre[tid] = acc;
  __syncthreads();

  float acc2 = fcb[tid];
#pragma unroll 4
  for (int c = 0; c < 256; ++c) acc2 += pre[c] * fcT[(size_t)c * 256 + tid];
  out[(size_t)(b * 256 + i) * 256 + tid] = acc2;
}

// ---------------------------------------------------------------- launcher
extern "C" void kernel_launch(void* const* d_in, const int* in_sizes, int n_in,
                              void* d_out, int out_size, void* d_ws, size_t ws_size,
                              hipStream_t stream) {
  (void)in_sizes; (void)n_in; (void)out_size; (void)ws_size;
  const float* q = (const float*)d_in[0];
  const float* k = (const float*)d_in[1];
  const float* v = (const float*)d_in[2];
  const float* amask = (const float*)d_in[3];
  const unsigned char* kpm = (const unsigned char*)d_in[4];
  const float* pitch = (const float*)d_in[5];
  const float* dur = (const float*)d_in[6];
  const float* Wq = (const float*)d_in[7];
  const float* Bq = (const float*)d_in[8];
  const float* Wk = (const float*)d_in[9];
  const float* Bk = (const float*)d_in[10];
  const float* Wv = (const float*)d_in[11];
  const float* Bv = (const float*)d_in[12];
  const float* fcw = (const float*)d_in[13];
  const float* fcb = (const float*)d_in[14];
  const float* prw = (const float*)d_in[15];
  const float* drw = (const float*)d_in[17];
  // pr_b (16) / dr_b (18) intentionally unused: j-constant logit offsets cancel in softmax.

  float* out = (float*)d_out;
  float* attn = out + 2 * 256 * 256;  // 131072

  float* wsf = (float*)d_ws;
  float* qh = wsf;              // 131072
  float* kh = qh + 131072;      // 131072
  float* vh = kh + 131072;      // 131072
  float* qpr = vh + 131072;     // 524288
  float* qdr = qpr + 524288;    // 524288
  float* fcT = qdr + 524288;    // 65536   (total ~6.03 MB)

  k_transpose<<<64, 256, 0, stream>>>(fcw, fcT);
  k_proj<<<96, 256, 0, stream>>>(q, k, v, Wq, Bq, Wk, Bk, Wv, Bv, qh, kh, vh);
  k_qprdr<<<256, 256, 0, stream>>>(qh, prw, drw, qpr, qdr);
  k_qk<<<128, 256, 0, stream>>>(qh, kh, attn);
  k_bias<<<4096, 256, 0, stream>>>(pitch, dur, qpr, qdr, amask, kpm, attn);
  k_pv_fc<<<512, 256, 0, stream>>>(attn, vh, fcT, fcb, out);
}